// Round 19
// baseline (62.023 us; speedup 1.0000x reference)
//
#include <hip/hip_runtime.h>
#include <math.h>
#include <stdint.h>

#define EPS 1e-5f

constexpr int Bc = 16, Cc = 32, Pc = 8, HIDc = 256, OUTc = 128;
constexpr int NBINS = 4096;
constexpr float NPC_INV = 1.0f / 2097152.0f;

// d_ws byte layout: [0,65536) stats (16384 f32) | [65536,196608) w_hh bf16 (65536 u16)
//                   | [196608,262144) w_out bf16 (32768 u16)
constexpr size_t WHH16_BYTE  = 65536;
constexpr size_t WOUT16_BYTE = 196608;

typedef float fx4 __attribute__((ext_vector_type(4)));

__device__ inline uint32_t bf16_rne(float f) {
    uint32_t u = __float_as_uint(f);
    return (u + 0x7fffu + ((u >> 16) & 1u)) >> 16;   // round-nearest-even
}

// ---------------- Kernel 1: unchanged from r18 (41 us stream + bf16 weight fold-in) ----------------
__global__ __launch_bounds__(256) void k1_stats(const float* __restrict__ x,
                                                float* __restrict__ ws,
                                                const float* __restrict__ w_hh,
                                                const float* __restrict__ w_out) {
    const int bid = blockIdx.x;
    const int t = threadIdx.x;

    if (bid < 192) {
        const bool hh = bid < 128;
        const float* src = hh ? w_hh : w_out;
        uint32_t* dst = (uint32_t*)((char*)ws + (hh ? WHH16_BYTE : WOUT16_BYTE));
        const int i = (hh ? bid : bid - 128) * 512 + t * 2;
        const float a = src[i], b = src[i + 1];
        dst[i >> 1] = bf16_rne(a) | (bf16_rne(b) << 16);
    }

    const fx4* px = reinterpret_cast<const fx4*>(x) + ((size_t)bid << 12);

    float vmax = -INFINITY, vmin = INFINITY, s = 0.f, ss = 0.f;
#pragma unroll
    for (int j = 0; j < 16; ++j) {
        fx4 v = __builtin_nontemporal_load(&px[j * 256 + t]);
        vmax = fmaxf(vmax, fmaxf(fmaxf(v.x, v.y), fmaxf(v.z, v.w)));
        vmin = fminf(vmin, fminf(fminf(v.x, v.y), fminf(v.z, v.w)));
        s += (v.x + v.y) + (v.z + v.w);
        ss = fmaf(v.x, v.x, ss); ss = fmaf(v.y, v.y, ss);
        ss = fmaf(v.z, v.z, ss); ss = fmaf(v.w, v.w, ss);
    }
#pragma unroll
    for (int off = 1; off < 64; off <<= 1) {
        vmax = fmaxf(vmax, __shfl_xor(vmax, off));
        vmin = fminf(vmin, __shfl_xor(vmin, off));
        s += __shfl_xor(s, off);
        ss += __shfl_xor(ss, off);
    }
    __shared__ float r[4][4];
    const int wid = t >> 6;
    if ((t & 63) == 0) { r[wid][0] = vmax; r[wid][1] = vmin; r[wid][2] = s; r[wid][3] = ss; }
    __syncthreads();
    if (t == 0) {
        vmax = fmaxf(fmaxf(r[0][0], r[1][0]), fmaxf(r[2][0], r[3][0]));
        vmin = fminf(fminf(r[0][1], r[1][1]), fminf(r[2][1], r[3][1]));
        s  = (r[0][2] + r[1][2]) + (r[2][2] + r[3][2]);
        ss = (r[0][3] + r[1][3]) + (r[2][3] + r[3][3]);
        ws[bid]             = vmax;
        ws[NBINS + bid]     = vmin;
        ws[2 * NBINS + bid] = s;
        ws[3 * NBINS + bid] = ss;
    }
}

// ---------------- Kernel 2: 1024 threads (16 waves = 2x TLP); quarter-row weights ----------------
// t: h = t>>2 (stage D output), q = t&3 (k-quarter, 64 wide, in-wave shfl reduce).
// Top burst: w_hh bf16 quarter (8 uint4) + w_out bf16 slice (4 uint4) + stats + biases.
// VGPR budget ~110 <= 128 cap (launch_bounds(1024,4)).
__global__ __launch_bounds__(1024, 4) void k2_rnn(const float* __restrict__ ws,
                                                  const float* __restrict__ bn_gamma,
                                                  const float* __restrict__ bn_beta,
                                                  const float* __restrict__ w_ih,
                                                  const float* __restrict__ b_ih,
                                                  const float* __restrict__ b_hh,
                                                  const float* __restrict__ b_out,
                                                  const float* __restrict__ ln_gamma,
                                                  const float* __restrict__ ln_beta,
                                                  float* __restrict__ out) {
    const int b = blockIdx.x;
    const int t = threadIdx.x;                 // 1024 threads
    const int h = t >> 2, q = t & 3;           // stage-D mapping
    const int oi = t >> 3, seg = t & 7;        // stage-E mapping

    const uint32_t* whh16  = (const uint32_t*)((const char*)ws + WHH16_BYTE);
    const uint32_t* wout16 = (const uint32_t*)((const char*)ws + WOUT16_BYTE);

    __shared__ float scale_s[Cc], shift_s[Cc];
    __shared__ float pA[4][Cc], pB[4][Cc];
    __shared__ __align__(16) float pooled[Pc][Cc];
    __shared__ __align__(16) float u[Pc][HIDc];
    __shared__ __align__(16) float hxs[2][288];   // word(k) = 36*(k>>5) + (k&31)
    __shared__ __align__(16) float o[OUTc];
    __shared__ float red2[2];

    // ===== TOP BURST =====
    uint4 wpk4[8];                                  // w_hh row h, quarter q (64 bf16)
    {
        const uint4* wr = reinterpret_cast<const uint4*>(whh16 + h * 128 + q * 32);
#pragma unroll
        for (int e = 0; e < 8; ++e) wpk4[e] = wr[e];
    }
    uint4 wopk[4];                                  // w_out row oi, 32-k slice seg
    {
        const uint4* wr = reinterpret_cast<const uint4*>(wout16 + oi * 128 + seg * 16);
#pragma unroll
        for (int e = 0; e < 4; ++e) wopk[e] = wr[e];
    }
    float xmaxv = 0.f, xminv = 0.f;
    if (t < 256) { xmaxv = ws[b * 256 + t]; xminv = ws[NBINS + b * 256 + t]; }
    const int h_c = t & 255;
    const float bias_c = b_ih[h_c] + b_hh[h_c];
    const float bout_e = (seg == 0) ? b_out[oi] : 0.f;
    float lng = 0.f, lnb = 0.f;
    if (t < OUTc) { lng = ln_gamma[t]; lnb = ln_beta[t]; }

    // ---- Stage A: channel stats; 1024 thr, c = (t>>3)&31 invariant ----
    {
        const float* sums = ws + 2 * NBINS;
        const float* sqs  = ws + 3 * NBINS;
        float s = 0.f, ss = 0.f;
#pragma unroll
        for (int j = 0; j < 4; ++j) {
            s  += sums[t + 1024 * j];
            ss += sqs[t + 1024 * j];
        }
#pragma unroll
        for (int off = 1; off < 8; off <<= 1) {
            s  += __shfl_xor(s, off);
            ss += __shfl_xor(ss, off);
        }
        if ((t & 7) == 0) {
            pA[t >> 8][(t >> 3) & 31] = s;
            pB[t >> 8][(t >> 3) & 31] = ss;
        }
    }
    __syncthreads();   // B1: drains the whole burst

    // ---- Unpack w_hh bf16 -> f32 regs (wpk4 dies here); scale/shift on t<32 ----
    float4 w4[16];
#pragma unroll
    for (int e = 0; e < 8; ++e) {
        const uint4 pk = wpk4[e];
        w4[2 * e].x     = __uint_as_float(pk.x << 16);
        w4[2 * e].y     = __uint_as_float(pk.x & 0xFFFF0000u);
        w4[2 * e].z     = __uint_as_float(pk.y << 16);
        w4[2 * e].w     = __uint_as_float(pk.y & 0xFFFF0000u);
        w4[2 * e + 1].x = __uint_as_float(pk.z << 16);
        w4[2 * e + 1].y = __uint_as_float(pk.z & 0xFFFF0000u);
        w4[2 * e + 1].z = __uint_as_float(pk.w << 16);
        w4[2 * e + 1].w = __uint_as_float(pk.w & 0xFFFF0000u);
    }
    if (t < Cc) {
        const float s  = pA[0][t] + pA[1][t] + pA[2][t] + pA[3][t];
        const float ss = pB[0][t] + pB[1][t] + pB[2][t] + pB[3][t];
        const float mean = s * NPC_INV;
        const float var  = ss * NPC_INV - mean * mean;
        const float sc   = bn_gamma[t] * rsqrtf(var + EPS);
        scale_s[t] = sc;
        shift_s[t] = bn_beta[t] - mean * sc;
    }
    __syncthreads();   // B2

    // ---- Stage B: pooled from prefetched stats ----
    if (t < 256) {
        const int c = t >> 3;
        const float sc = scale_s[c];
        const float xm = (sc >= 0.f) ? xmaxv : xminv;
        pooled[t & 7][c] = fmaxf(fmaf(sc, xm, shift_s[c]), 0.f);
    }
    __syncthreads();   // B3

    // ---- Stage C: u[p][h_c]; 4 p-groups x 2 p each (w_ih inline; L2 dedupes 4x) ----
    {
        const int pg = t >> 8;
        const float4* wi = reinterpret_cast<const float4*>(w_ih) + h_c * (Cc / 4);
        float4 wiv[8];
#pragma unroll
        for (int e = 0; e < 8; ++e) wiv[e] = wi[e];
        float u0 = 0.f;
#pragma unroll
        for (int pp = 0; pp < 2; ++pp) {
            const int p = pg * 2 + pp;
            const float4* pl = reinterpret_cast<const float4*>(&pooled[p][0]);
            float a0 = bias_c, a1 = 0.f, a2 = 0.f, a3 = 0.f;
#pragma unroll
            for (int e = 0; e < 8; ++e) {
                float4 pv = pl[e];
                a0 = fmaf(pv.x, wiv[e].x, a0);
                a1 = fmaf(pv.y, wiv[e].y, a1);
                a2 = fmaf(pv.z, wiv[e].z, a2);
                a3 = fmaf(pv.w, wiv[e].w, a3);
            }
            const float uv = (a0 + a1) + (a2 + a3);
            u[p][h_c] = uv;
            if (pp == 0) u0 = uv;
        }
        if (pg == 0) hxs[0][36 * (h_c >> 5) + (h_c & 31)] = fmaxf(u0, 0.f);  // step 0
    }
    __syncthreads();   // B4

    // ---- Stage D: 7 steps; per thread 64-k quarter; 4-float4 chunked reads ----
    int cur = 0;
    for (int step = 1; step < Pc; ++step) {
        // quarter base: k = 64q -> word 72q; float4 e at word 72q + 36*(e>>3) + 4*(e&7)
        const float* hbase = &hxs[cur][72 * q];
        float a0 = 0.f, a1 = 0.f, a2 = 0.f, a3 = 0.f;
#pragma unroll
        for (int c4 = 0; c4 < 4; ++c4) {         // 4 chunks of 4 float4 (caps live regs)
            float4 hv[4];
#pragma unroll
            for (int e = 0; e < 4; ++e) {
                const int ee = c4 * 4 + e;
                hv[e] = *reinterpret_cast<const float4*>(hbase + 36 * (ee >> 3) + 4 * (ee & 7));
            }
#pragma unroll
            for (int e = 0; e < 4; ++e) {
                const float4 wv = w4[c4 * 4 + e];
                a0 = fmaf(hv[e].x, wv.x, a0);
                a1 = fmaf(hv[e].y, wv.y, a1);
                a2 = fmaf(hv[e].z, wv.z, a2);
                a3 = fmaf(hv[e].w, wv.w, a3);
            }
        }
        float acc = (a0 + a1) + (a2 + a3);
        acc += __shfl_xor(acc, 1);
        acc += __shfl_xor(acc, 2);
        if (q == 0) {
            const float v = u[step][h] + acc;
            hxs[cur ^ 1][36 * (h >> 5) + (h & 31)] = fmaxf(v, 0.f);
        }
        __syncthreads();
        cur ^= 1;
    }
    // final hx in hxs[1]

    // ---- Stage E: out-proj from prefetched bf16 regs; 8 lanes per output ----
    {
        float a0 = bout_e, a1 = 0.f, a2 = 0.f, a3 = 0.f;
#pragma unroll
        for (int e = 0; e < 4; ++e) {            // k = 32*seg + 8e + 0..7
            const uint4 pk = wopk[e];
            const int base = 36 * seg + 8 * e;
            const float4 hv0 = *reinterpret_cast<const float4*>(&hxs[1][base]);
            const float4 hv1 = *reinterpret_cast<const float4*>(&hxs[1][base + 4]);
            a0 = fmaf(hv0.x, __uint_as_float(pk.x << 16), a0);
            a1 = fmaf(hv0.y, __uint_as_float(pk.x & 0xFFFF0000u), a1);
            a2 = fmaf(hv0.z, __uint_as_float(pk.y << 16), a2);
            a3 = fmaf(hv0.w, __uint_as_float(pk.y & 0xFFFF0000u), a3);
            a0 = fmaf(hv1.x, __uint_as_float(pk.z << 16), a0);
            a1 = fmaf(hv1.y, __uint_as_float(pk.z & 0xFFFF0000u), a1);
            a2 = fmaf(hv1.z, __uint_as_float(pk.w << 16), a2);
            a3 = fmaf(hv1.w, __uint_as_float(pk.w & 0xFFFF0000u), a3);
        }
        float s = (a0 + a1) + (a2 + a3);
        s += __shfl_xor(s, 1);
        s += __shfl_xor(s, 2);
        s += __shfl_xor(s, 4);
        if (seg == 0) o[oi] = s;
    }
    __syncthreads();

    // ---- LayerNorm over 128 ----
    if (t < 64) {
        const float x0 = o[t], x1 = o[t + 64];
        float s = x0 + x1, ss = x0 * x0 + x1 * x1;
#pragma unroll
        for (int off = 1; off < 64; off <<= 1) {
            s  += __shfl_xor(s, off);
            ss += __shfl_xor(ss, off);
        }
        if (t == 0) { red2[0] = s; red2[1] = ss; }
    }
    __syncthreads();
    if (t < OUTc) {
        const float mu  = red2[0] * (1.0f / OUTc);
        const float var = red2[1] * (1.0f / OUTc) - mu * mu;
        const float rs  = rsqrtf(var + EPS);
        out[b * OUTc + t] = (o[t] - mu) * rs * lng + lnb;
    }
}

extern "C" void kernel_launch(void* const* d_in, const int* in_sizes, int n_in,
                              void* d_out, int out_size, void* d_ws, size_t ws_size,
                              hipStream_t stream) {
    const float* x        = (const float*)d_in[0];
    const float* bn_gamma = (const float*)d_in[1];
    const float* bn_beta  = (const float*)d_in[2];
    const float* w_ih     = (const float*)d_in[3];
    const float* b_ih     = (const float*)d_in[4];
    const float* w_hh     = (const float*)d_in[5];
    const float* b_hh     = (const float*)d_in[6];
    const float* w_out    = (const float*)d_in[7];
    const float* b_out    = (const float*)d_in[8];
    const float* ln_gamma = (const float*)d_in[9];
    const float* ln_beta  = (const float*)d_in[10];
    float* out = (float*)d_out;
    float* ws  = (float*)d_ws;

    k1_stats<<<NBINS, 256, 0, stream>>>(x, ws, w_hh, w_out);
    k2_rnn<<<Bc, 1024, 0, stream>>>(ws, bn_gamma, bn_beta, w_ih, b_ih, b_hh,
                                    b_out, ln_gamma, ln_beta, out);
}

// Round 20
// 60.912 us; speedup vs baseline: 1.0183x; 1.0183x over previous
//
#include <hip/hip_runtime.h>
#include <math.h>
#include <stdint.h>

#define EPS 1e-5f

constexpr int Bc = 16, Cc = 32, Pc = 8, HIDc = 256, OUTc = 128;
constexpr int NBINS = 4096;
constexpr float NPC_INV = 1.0f / 2097152.0f;

// d_ws byte layout: [0,65536) stats (16384 f32) | [65536,196608) w_hh bf16 (65536 u16)
//                   | [196608,262144) w_out bf16 (32768 u16).  Requires ws_size >= 256 KB.
constexpr size_t WHH16_BYTE  = 65536;
constexpr size_t WOUT16_BYTE = 196608;

typedef float fx4 __attribute__((ext_vector_type(4)));

__device__ inline uint32_t bf16_rne(float f) {
    uint32_t u = __float_as_uint(f);
    return (u + 0x7fffu + ((u >> 16) & 1u)) >> 16;   // round-nearest-even
}

// ---------------- Kernel 1: r8's streaming body + weight->bf16 fold-in ----------------
// Blocks 0..127 convert a 512-elem slice of w_hh; blocks 128..191 a slice of w_out.
// Then all 4096 blocks stream their bin (41 us = 6.5 TB/s, at read ceiling).
__global__ __launch_bounds__(256) void k1_stats(const float* __restrict__ x,
                                                float* __restrict__ ws,
                                                const float* __restrict__ w_hh,
                                                const float* __restrict__ w_out) {
    const int bid = blockIdx.x;
    const int t = threadIdx.x;

    if (bid < 192) {
        const bool hh = bid < 128;
        const float* src = hh ? w_hh : w_out;
        uint32_t* dst = (uint32_t*)((char*)ws + (hh ? WHH16_BYTE : WOUT16_BYTE));
        const int i = (hh ? bid : bid - 128) * 512 + t * 2;
        const float a = src[i], b = src[i + 1];
        dst[i >> 1] = bf16_rne(a) | (bf16_rne(b) << 16);
    }

    const fx4* px = reinterpret_cast<const fx4*>(x) + ((size_t)bid << 12);

    float vmax = -INFINITY, vmin = INFINITY, s = 0.f, ss = 0.f;
#pragma unroll
    for (int j = 0; j < 16; ++j) {
        fx4 v = __builtin_nontemporal_load(&px[j * 256 + t]);
        vmax = fmaxf(vmax, fmaxf(fmaxf(v.x, v.y), fmaxf(v.z, v.w)));
        vmin = fminf(vmin, fminf(fminf(v.x, v.y), fminf(v.z, v.w)));
        s += (v.x + v.y) + (v.z + v.w);
        ss = fmaf(v.x, v.x, ss); ss = fmaf(v.y, v.y, ss);
        ss = fmaf(v.z, v.z, ss); ss = fmaf(v.w, v.w, ss);
    }
#pragma unroll
    for (int off = 1; off < 64; off <<= 1) {
        vmax = fmaxf(vmax, __shfl_xor(vmax, off));
        vmin = fminf(vmin, __shfl_xor(vmin, off));
        s += __shfl_xor(s, off);
        ss += __shfl_xor(ss, off);
    }
    __shared__ float r[4][4];
    const int wid = t >> 6;
    if ((t & 63) == 0) { r[wid][0] = vmax; r[wid][1] = vmin; r[wid][2] = s; r[wid][3] = ss; }
    __syncthreads();
    if (t == 0) {
        vmax = fmaxf(fmaxf(r[0][0], r[1][0]), fmaxf(r[2][0], r[3][0]));
        vmin = fminf(fminf(r[0][1], r[1][1]), fminf(r[2][1], r[3][1]));
        s  = (r[0][2] + r[1][2]) + (r[2][2] + r[3][2]);
        ss = (r[0][3] + r[1][3]) + (r[2][3] + r[3][3]);
        ws[bid]             = vmax;
        ws[NBINS + bid]     = vmin;
        ws[2 * NBINS + bid] = s;
        ws[3 * NBINS + bid] = ss;
    }
}

// ---------------- Kernel 2: r8 structure; weights fetched as bf16 (half bytes) ----------------
__global__ __launch_bounds__(512, 2) void k2_rnn(const float* __restrict__ ws,
                                                 const float* __restrict__ bn_gamma,
                                                 const float* __restrict__ bn_beta,
                                                 const float* __restrict__ w_ih,
                                                 const float* __restrict__ b_ih,
                                                 const float* __restrict__ b_hh,
                                                 const float* __restrict__ b_out,
                                                 const float* __restrict__ ln_gamma,
                                                 const float* __restrict__ ln_beta,
                                                 float* __restrict__ out) {
    const int b = blockIdx.x;
    const int t = threadIdx.x;                 // 512 threads
    const int og = t >> 3, kg = t & 7;

    const uint32_t* whh16  = (const uint32_t*)((const char*)ws + WHH16_BYTE);
    const uint32_t* wout16 = (const uint32_t*)((const char*)ws + WOUT16_BYTE);

    __shared__ float scale_s[Cc], shift_s[Cc];
    __shared__ float pA[2][Cc], pB[2][Cc];
    __shared__ __align__(16) float pooled[Pc][Cc];
    __shared__ __align__(16) float u[Pc][HIDc];
    __shared__ __align__(16) float hxs[2][288];   // word(k) = 36*(k>>5) + (k&31)
    __shared__ __align__(16) float o[OUTc];
    __shared__ float red2[2];

    // ---- Stage A: channel stats (coalesced; c = (t>>3)&31 invariant) ----
    {
        const float* sums = ws + 2 * NBINS;
        const float* sqs  = ws + 3 * NBINS;
        float s = 0.f, ss = 0.f;
#pragma unroll
        for (int j = 0; j < 8; ++j) {
            s  += sums[t + 512 * j];
            ss += sqs[t + 512 * j];
        }
#pragma unroll
        for (int off = 1; off < 8; off <<= 1) {
            s  += __shfl_xor(s, off);
            ss += __shfl_xor(ss, off);
        }
        if ((t & 7) == 0) {
            pA[t >> 8][(t >> 3) & 31] = s;
            pB[t >> 8][(t >> 3) & 31] = ss;
        }
    }

    // ---- Issue packed w_hh tile loads ----
    uint32_t wpk[4][16];
#pragma unroll
    for (int r = 0; r < 4; ++r) {
        const uint4* wrow = reinterpret_cast<const uint4*>(whh16 + (4 * og + r) * 128 + 16 * kg);
#pragma unroll
        for (int q = 0; q < 4; ++q) {
            uint4 v = wrow[q];
            wpk[r][4 * q + 0] = v.x; wpk[r][4 * q + 1] = v.y;
            wpk[r][4 * q + 2] = v.z; wpk[r][4 * q + 3] = v.w;
        }
    }

    __syncthreads();   // B1: drains stage-A reads + packed weight loads

    // ---- Unpack bf16 -> f32 registers in the t<32 dead window ----
    float4 w4[4][8];
#pragma unroll
    for (int r = 0; r < 4; ++r) {
#pragma unroll
        for (int e = 0; e < 8; ++e) {
            const uint32_t u0 = wpk[r][2 * e], u1 = wpk[r][2 * e + 1];
            w4[r][e].x = __uint_as_float(u0 << 16);
            w4[r][e].y = __uint_as_float(u0 & 0xFFFF0000u);
            w4[r][e].z = __uint_as_float(u1 << 16);
            w4[r][e].w = __uint_as_float(u1 & 0xFFFF0000u);
        }
    }
    if (t < Cc) {
        const float s = pA[0][t] + pA[1][t], ss = pB[0][t] + pB[1][t];
        const float mean = s * NPC_INV;
        const float var  = ss * NPC_INV - mean * mean;
        const float sc   = bn_gamma[t] * rsqrtf(var + EPS);
        scale_s[t] = sc;
        shift_s[t] = bn_beta[t] - mean * sc;
    }
    __syncthreads();   // B2

    // ---- Stage B: pooled (bin = b*256 + t, coalesced) ----
    if (t < 256) {
        const int c = t >> 3;
        const int bin = b * 256 + t;
        const float sc = scale_s[c];
        const float xm = (sc >= 0.f) ? ws[bin] : ws[NBINS + bin];
        pooled[t & 7][c] = fmaxf(fmaf(sc, xm, shift_s[c]), 0.f);
    }
    __syncthreads();   // B3

    // ---- Stage C: u[p][h]; w_ih from global f32 (8-wave TLP covers it) ----
    {
        const int h = t & 255, pg = t >> 8;
        const float4* wi = reinterpret_cast<const float4*>(w_ih) + h * (Cc / 4);
        float4 wiv[8];
#pragma unroll
        for (int e = 0; e < 8; ++e) wiv[e] = wi[e];
        const float bias = b_ih[h] + b_hh[h];
        float u0 = 0.f;
#pragma unroll
        for (int pp = 0; pp < 4; ++pp) {
            const int p = pg * 4 + pp;
            const float4* pl = reinterpret_cast<const float4*>(&pooled[p][0]);
            float a0 = bias, a1 = 0.f, a2 = 0.f, a3 = 0.f;
#pragma unroll
            for (int e = 0; e < 8; ++e) {
                float4 pv = pl[e];
                a0 = fmaf(pv.x, wiv[e].x, a0);
                a1 = fmaf(pv.y, wiv[e].y, a1);
                a2 = fmaf(pv.z, wiv[e].z, a2);
                a3 = fmaf(pv.w, wiv[e].w, a3);
            }
            const float uv = (a0 + a1) + (a2 + a3);
            u[p][h] = uv;
            if (pp == 0) u0 = uv;
        }
        if (pg == 0) hxs[0][36 * (h >> 5) + (h & 31)] = fmaxf(u0, 0.f);  // step 0
    }
    __syncthreads();   // B4

    // ---- Stage D: 7 recurrent steps, one barrier each (w4 resident in f32 regs) ----
    int cur = 0;
    for (int step = 1; step < Pc; ++step) {
        float4 h4[8];
        const float4* hp = reinterpret_cast<const float4*>(&hxs[cur][kg * 36]);
#pragma unroll
        for (int e = 0; e < 8; ++e) h4[e] = hp[e];
        float acc[4];
#pragma unroll
        for (int r = 0; r < 4; ++r) {
            float a0 = 0.f, a1 = 0.f, a2 = 0.f, a3 = 0.f;
#pragma unroll
            for (int e = 0; e < 8; ++e) {
                float4 wv = w4[r][e], hv = h4[e];
                a0 = fmaf(hv.x, wv.x, a0);
                a1 = fmaf(hv.y, wv.y, a1);
                a2 = fmaf(hv.z, wv.z, a2);
                a3 = fmaf(hv.w, wv.w, a3);
            }
            acc[r] = (a0 + a1) + (a2 + a3);
        }
#pragma unroll
        for (int off = 1; off < 8; off <<= 1) {
#pragma unroll
            for (int r = 0; r < 4; ++r) acc[r] += __shfl_xor(acc[r], off);
        }
        if (kg == 0) {
#pragma unroll
            for (int r = 0; r < 4; ++r) {
                const int h = 4 * og + r;
                const float v = u[step][h] + acc[r];
                hxs[cur ^ 1][36 * (h >> 5) + (h & 31)] = fmaxf(v, 0.f);
            }
        }
        __syncthreads();
        cur ^= 1;
    }
    // final hx in hxs[1]

    // ---- Stage E: out-proj; w_out read as bf16 from ws (64 KB/block), unpack inline ----
    {
        const int oi = t >> 2, seg = t & 3;
        const uint4* wop = reinterpret_cast<const uint4*>(wout16) + oi * 32 + seg * 8;
        float a0 = ((t & 3) == 0) ? b_out[oi] : 0.f, a1 = 0.f, a2 = 0.f, a3 = 0.f;
#pragma unroll
        for (int e = 0; e < 8; ++e) {
            const uint4 pk = wop[e];
            const int k = seg * 64 + e * 8;
            const int base = 36 * (k >> 5) + (k & 31);
            const float4 hv0 = *reinterpret_cast<const float4*>(&hxs[1][base]);
            const float4 hv1 = *reinterpret_cast<const float4*>(&hxs[1][base + 4]);
            a0 = fmaf(hv0.x, __uint_as_float(pk.x << 16), a0);
            a1 = fmaf(hv0.y, __uint_as_float(pk.x & 0xFFFF0000u), a1);
            a2 = fmaf(hv0.z, __uint_as_float(pk.y << 16), a2);
            a3 = fmaf(hv0.w, __uint_as_float(pk.y & 0xFFFF0000u), a3);
            a0 = fmaf(hv1.x, __uint_as_float(pk.z << 16), a0);
            a1 = fmaf(hv1.y, __uint_as_float(pk.z & 0xFFFF0000u), a1);
            a2 = fmaf(hv1.z, __uint_as_float(pk.w << 16), a2);
            a3 = fmaf(hv1.w, __uint_as_float(pk.w & 0xFFFF0000u), a3);
        }
        float s = (a0 + a1) + (a2 + a3);
        s += __shfl_xor(s, 1);
        s += __shfl_xor(s, 2);
        if (seg == 0) o[oi] = s;
    }
    __syncthreads();

    // ---- LayerNorm over 128 ----
    if (t < 64) {
        const float x0 = o[t], x1 = o[t + 64];
        float s = x0 + x1, ss = x0 * x0 + x1 * x1;
#pragma unroll
        for (int off = 1; off < 64; off <<= 1) {
            s  += __shfl_xor(s, off);
            ss += __shfl_xor(ss, off);
        }
        if (t == 0) { red2[0] = s; red2[1] = ss; }
    }
    __syncthreads();
    if (t < OUTc) {
        const float mu  = red2[0] * (1.0f / OUTc);
        const float var = red2[1] * (1.0f / OUTc) - mu * mu;
        const float rs  = rsqrtf(var + EPS);
        out[b * OUTc + t] = (o[t] - mu) * rs * ln_gamma[t] + ln_beta[t];
    }
}

extern "C" void kernel_launch(void* const* d_in, const int* in_sizes, int n_in,
                              void* d_out, int out_size, void* d_ws, size_t ws_size,
                              hipStream_t stream) {
    const float* x        = (const float*)d_in[0];
    const float* bn_gamma = (const float*)d_in[1];
    const float* bn_beta  = (const float*)d_in[2];
    const float* w_ih     = (const float*)d_in[3];
    const float* b_ih     = (const float*)d_in[4];
    const float* w_hh     = (const float*)d_in[5];
    const float* b_hh     = (const float*)d_in[6];
    const float* w_out    = (const float*)d_in[7];
    const float* b_out    = (const float*)d_in[8];
    const float* ln_gamma = (const float*)d_in[9];
    const float* ln_beta  = (const float*)d_in[10];
    float* out = (float*)d_out;
    float* ws  = (float*)d_ws;

    k1_stats<<<NBINS, 256, 0, stream>>>(x, ws, w_hh, w_out);
    k2_rnn<<<Bc, 512, 0, stream>>>(ws, bn_gamma, bn_beta, w_ih, b_ih, b_hh,
                                   b_out, ln_gamma, ln_beta, out);
}